// Round 2
// baseline (1686.707 us; speedup 1.0000x reference)
//
#include <hip/hip_runtime.h>
#include <hip/hip_bf16.h>

typedef unsigned int uint;
typedef unsigned short ushort;

#define Tn 128
#define Bn 16
#define HH 128
#define G3 384
#define DIN 1024

__device__ __forceinline__ float lo16(uint u){ union{uint i; float f;} c; c.i = u << 16; return c.f; }
__device__ __forceinline__ float hi16(uint u){ union{uint i; float f;} c; c.i = u & 0xffff0000u; return c.f; }
__device__ __forceinline__ ushort f2bf(float f){
    union{float f; uint u;} c; c.f = f;
    uint u = c.u + 0x7fffu + ((c.u >> 16) & 1u);   // RNE to bf16
    return (ushort)(u >> 16);
}
__device__ __forceinline__ uint pack2(float a, float b){
    return ((uint)f2bf(b) << 16) | (uint)f2bf(a);
}
__device__ __forceinline__ float sigm(float x){ return 1.f/(1.f + __expf(-x)); }
__device__ __forceinline__ float tanhx(float x){
    float t = __expf(-2.f*fabsf(x));
    float r = (1.f - t)/(1.f + t);
    return x >= 0.f ? r : -r;
}

// dot of 128: packed-bf16 weight row (64 uints in regs) with fp32 vector in LDS
__device__ __forceinline__ float dot128(const uint* wr, const float* hL){
    float acc = 0.f;
    const float4* h4p = (const float4*)hL;
#pragma unroll
    for (int c = 0; c < 32; ++c){
        float4 h4 = h4p[c];
        uint w0 = wr[2*c], w1 = wr[2*c+1];
        acc = fmaf(lo16(w0), h4.x, acc);
        acc = fmaf(hi16(w0), h4.y, acc);
        acc = fmaf(lo16(w1), h4.z, acc);
        acc = fmaf(hi16(w1), h4.w, acc);
    }
    return acc;
}

// load one 128-float row, pack to 64 bf16-pair uints in registers
__device__ __forceinline__ void load_row_bf(const float* wrow, uint* wr){
    const float4* wp = (const float4*)wrow;
#pragma unroll
    for (int c = 0; c < 32; ++c){
        float4 q = wp[c];
        wr[2*c]   = pack2(q.x, q.y);
        wr[2*c+1] = pack2(q.z, q.w);
    }
}

// ---------------- emb = x @ W_emb^T : (2048,1024)@(1024,128) -> (2048,128) fp32
// 512 blocks x 128 threads, 4 rows per block. W_emb L2-resident.
__global__ __launch_bounds__(128) void k_emb(const float* __restrict__ x,
                                             const float* __restrict__ Wemb,
                                             float* __restrict__ emb){
    __shared__ __align__(16) float xL[4*DIN];
    int tid = threadIdx.x;
    int row0 = blockIdx.x * 4;
#pragma unroll
    for (int r = 0; r < 4; ++r){
        const float4* src = (const float4*)(x + (size_t)(row0 + r)*DIN);
        float4* dst = (float4*)&xL[r*DIN];
        dst[tid]       = src[tid];
        dst[tid + 128] = src[tid + 128];
    }
    __syncthreads();
    int e = tid;
    float acc0=0.f, acc1=0.f, acc2=0.f, acc3=0.f;
    const float4* wp = (const float4*)(Wemb + (size_t)e*DIN);
#pragma unroll 4
    for (int c = 0; c < 128; ++c){
        float4 qa = wp[2*c], qb = wp[2*c+1];   // 8 weights
        int d0 = c*8;
        {
            float4 a = *(const float4*)&xL[0*DIN + d0];
            float4 b = *(const float4*)&xL[0*DIN + d0 + 4];
            acc0 = fmaf(qa.x,a.x,fmaf(qa.y,a.y,fmaf(qa.z,a.z,fmaf(qa.w,a.w,acc0))));
            acc0 = fmaf(qb.x,b.x,fmaf(qb.y,b.y,fmaf(qb.z,b.z,fmaf(qb.w,b.w,acc0))));
        }
        {
            float4 a = *(const float4*)&xL[1*DIN + d0];
            float4 b = *(const float4*)&xL[1*DIN + d0 + 4];
            acc1 = fmaf(qa.x,a.x,fmaf(qa.y,a.y,fmaf(qa.z,a.z,fmaf(qa.w,a.w,acc1))));
            acc1 = fmaf(qb.x,b.x,fmaf(qb.y,b.y,fmaf(qb.z,b.z,fmaf(qb.w,b.w,acc1))));
        }
        {
            float4 a = *(const float4*)&xL[2*DIN + d0];
            float4 b = *(const float4*)&xL[2*DIN + d0 + 4];
            acc2 = fmaf(qa.x,a.x,fmaf(qa.y,a.y,fmaf(qa.z,a.z,fmaf(qa.w,a.w,acc2))));
            acc2 = fmaf(qb.x,b.x,fmaf(qb.y,b.y,fmaf(qb.z,b.z,fmaf(qb.w,b.w,acc2))));
        }
        {
            float4 a = *(const float4*)&xL[3*DIN + d0];
            float4 b = *(const float4*)&xL[3*DIN + d0 + 4];
            acc3 = fmaf(qa.x,a.x,fmaf(qa.y,a.y,fmaf(qa.z,a.z,fmaf(qa.w,a.w,acc3))));
            acc3 = fmaf(qb.x,b.x,fmaf(qb.y,b.y,fmaf(qb.z,b.z,fmaf(qb.w,b.w,acc3))));
        }
    }
    emb[(size_t)(row0+0)*HH + e] = acc0;
    emb[(size_t)(row0+1)*HH + e] = acc1;
    emb[(size_t)(row0+2)*HH + e] = acc2;
    emb[(size_t)(row0+3)*HH + e] = acc3;
}

// ---------------- Gi = emb @ Wih^T + bih for both GRUs: (2048,384) each
// 256 blocks x 768 threads, 8 rows per block.
__global__ __launch_bounds__(768) void k_gi(const float* __restrict__ emb,
                                            const float* __restrict__ Wiha,
                                            const float* __restrict__ biha,
                                            const float* __restrict__ Wihb,
                                            const float* __restrict__ bihb,
                                            float* __restrict__ gia,
                                            float* __restrict__ gib){
    __shared__ __align__(16) float eL[8*HH];
    int tid = threadIdx.x;
    int row0 = blockIdx.x * 8;
    if (tid < 256)
        ((float4*)eL)[tid] = ((const float4*)(emb + (size_t)row0*HH))[tid];
    int g = (tid < G3) ? tid : tid - G3;
    const float* wrow = (tid < G3) ? (Wiha + (size_t)g*HH) : (Wihb + (size_t)g*HH);
    float bias = (tid < G3) ? biha[g] : bihb[g];
    uint wr[64];
    load_row_bf(wrow, wr);
    __syncthreads();
    float* dst = (tid < G3) ? gia : gib;
#pragma unroll
    for (int r = 0; r < 8; ++r){
        float acc = dot128(wr, &eL[r*HH]) + bias;
        dst[(size_t)(row0 + r)*G3 + g] = acc;
    }
}

// ---------------- Phase 1: GRU-a recurrence per (b,i), emit s[k] = 0.5*Wa.h + ba
__global__ __launch_bounds__(384) void k_gru_a(const float* __restrict__ Whh,
                                               const float* __restrict__ bhh,
                                               const float* __restrict__ Wa,
                                               const float* __restrict__ ba,
                                               const float* __restrict__ Gi,
                                               float* __restrict__ sW){
    __shared__ __align__(16) float hL[HH];
    __shared__ float ghL[G3], giL[G3];
    __shared__ float redL[2];
    int tid = threadIdx.x;
    int i = Tn - 1 - blockIdx.x;   // longest blocks first
    int b = blockIdx.y;
    int row = b*Tn + i;

    uint wr[64];
    load_row_bf(Whh + (size_t)tid*HH, wr);
    float bhh_g = bhh[tid];
    float Wa_j  = (tid < HH) ? Wa[tid] : 0.f;
    float bav   = ba[0];
    if (tid < HH) hL[tid] = 0.f;
    __syncthreads();

    for (int k = 0; k <= i; ++k){
        int pos = i - k;
        float giv = Gi[(size_t)(b*Tn + pos)*G3 + tid];
        float acc = bhh_g + dot128(wr, hL);
        ghL[tid] = acc; giL[tid] = giv;
        __syncthreads();
        if (tid < HH){
            float r = sigm(giL[tid]        + ghL[tid]);
            float z = sigm(giL[HH + tid]   + ghL[HH + tid]);
            float n = tanhx(giL[2*HH + tid] + r*ghL[2*HH + tid]);
            float hnew = (1.f - z)*n + z*hL[tid];
            hL[tid] = hnew;
            float p = Wa_j * hnew;
#pragma unroll
            for (int off = 32; off; off >>= 1) p += __shfl_down(p, off);
            if ((tid & 63) == 0) redL[tid >> 6] = p;
        }
        __syncthreads();
        if (tid == 0) sW[(size_t)row*Tn + k] = 0.5f*(redL[0] + redL[1]) + bav;
    }
}

// ---------------- Phase 2: GRU-b recurrence + softmax + beta + context + logit
// 512 threads: 0-383 gh matvec + gate update; 384-511 Wb matvec / c accumulation.
__global__ __launch_bounds__(512) void k_gru_b(const float* __restrict__ Whh,
                                               const float* __restrict__ bhh,
                                               const float* __restrict__ Wb,
                                               const float* __restrict__ bb,
                                               const float* __restrict__ Wo,
                                               const float* __restrict__ bo,
                                               const float* __restrict__ Gi,
                                               const float* __restrict__ emb,
                                               const float* __restrict__ sW,
                                               float* __restrict__ out){
    __shared__ __align__(16) float hL[HH];
    __shared__ float ghL[G3], giL[G3];
    __shared__ float aL[Tn];
    __shared__ float red[4];
    int tid = threadIdx.x;
    int i = Tn - 1 - blockIdx.x;
    int b = blockIdx.y;
    int row = b*Tn + i;
    int e = tid - G3;

    const float* wsrc = (tid < G3) ? (Whh + (size_t)tid*HH) : (Wb + (size_t)e*HH);
    uint wr[64];
    load_row_bf(wsrc, wr);
    float bhh_g = (tid < G3) ? bhh[tid] : 0.f;
    float bb_e  = (tid >= G3) ? bb[e] : 0.f;
    float Wo_e  = (tid >= G3) ? Wo[e] : 0.f;
    float bov   = bo[0];

    if (tid < HH) hL[tid] = 0.f;
    if (tid < Tn) aL[tid] = (tid <= i) ? sW[(size_t)row*Tn + tid] : -1e30f;
    __syncthreads();
    if (tid == 0){
        float m = -1e30f;
        for (int k2 = 0; k2 <= i; ++k2) m = fmaxf(m, aL[k2]);
        red[0] = m;
    }
    __syncthreads();
    float m = red[0];
    if (tid < Tn) aL[tid] = __expf(aL[tid] - m);   // invalid entries -> 0
    __syncthreads();
    if (tid == 0){
        float d = 0.f;
        for (int k2 = 0; k2 <= i; ++k2) d += aL[k2];
        red[1] = d;
    }
    // red[1] is ordered before its only use (after the loop) by the loop barriers.

    float c_acc = 0.f;   // threads >= G3: context element e (unnormalized)
    for (int k = 0; k <= i; ++k){
        int pos = i - k;
        if (tid >= G3){
            if (k > 0){   // deferred step k-1: h currently = hs[k-1]
                float ev = emb[(size_t)(b*Tn + pos + 1)*HH + e];
                float pb = dot128(wr, hL);
                float beta = tanhx(0.5f*pb + bb_e);
                c_acc = fmaf(aL[k-1]*beta, ev, c_acc);
            }
        } else {
            float giv = Gi[(size_t)(b*Tn + pos)*G3 + tid];
            float acc = bhh_g + dot128(wr, hL);
            ghL[tid] = acc; giL[tid] = giv;
        }
        __syncthreads();
        if (tid < HH){
            float r = sigm(giL[tid]        + ghL[tid]);
            float z = sigm(giL[HH + tid]   + ghL[HH + tid]);
            float n = tanhx(giL[2*HH + tid] + r*ghL[2*HH + tid]);
            hL[tid] = (1.f - z)*n + z*hL[tid];
        }
        __syncthreads();
    }
    // final step k = i: h = hs[i], input position 0
    if (tid >= G3){
        float ev = emb[(size_t)(b*Tn + 0)*HH + e];
        float pb = dot128(wr, hL);
        float beta = tanhx(0.5f*pb + bb_e);
        c_acc = fmaf(aL[i]*beta, ev, c_acc);
        float p = Wo_e * c_acc;
#pragma unroll
        for (int off = 32; off; off >>= 1) p += __shfl_down(p, off);
        if ((e & 63) == 0) red[2 + (e >> 6)] = p;
    }
    __syncthreads();
    if (tid == G3){
        out[row] = (red[2] + red[3]) / red[1] + bov;
    }
}

extern "C" void kernel_launch(void* const* d_in, const int* in_sizes, int n_in,
                              void* d_out, int out_size, void* d_ws, size_t ws_size,
                              hipStream_t stream) {
    const float* x     = (const float*)d_in[0];
    const float* Wemb  = (const float*)d_in[1];
    const float* Wih_a = (const float*)d_in[2];
    const float* Whh_a = (const float*)d_in[3];
    const float* bih_a = (const float*)d_in[4];
    const float* bhh_a = (const float*)d_in[5];
    const float* Wa    = (const float*)d_in[6];
    const float* ba    = (const float*)d_in[7];
    const float* Wih_b = (const float*)d_in[8];
    const float* Whh_b = (const float*)d_in[9];
    const float* bih_b = (const float*)d_in[10];
    const float* bhh_b = (const float*)d_in[11];
    const float* Wb    = (const float*)d_in[12];
    const float* bb    = (const float*)d_in[13];
    const float* Wo    = (const float*)d_in[14];
    const float* bo    = (const float*)d_in[15];

    const int NR = Bn*Tn;            // 2048 rows
    float* embW = (float*)d_ws;                   // 2048*128
    float* giA  = embW + (size_t)NR*HH;           // 2048*384
    float* giB  = giA  + (size_t)NR*G3;           // 2048*384
    float* sW   = giB  + (size_t)NR*G3;           // 2048*128

    k_emb<<<dim3(NR/4), 128, 0, stream>>>(x, Wemb, embW);
    k_gi <<<dim3(NR/8), 768, 0, stream>>>(embW, Wih_a, bih_a, Wih_b, bih_b, giA, giB);
    k_gru_a<<<dim3(Tn, Bn), 384, 0, stream>>>(Whh_a, bhh_a, Wa, ba, giA, sW);
    k_gru_b<<<dim3(Tn, Bn), 512, 0, stream>>>(Whh_b, bhh_b, Wb, bb, Wo, bo,
                                              giB, embW, sW, (float*)d_out);
}

// Round 3
// 921.754 us; speedup vs baseline: 1.8299x; 1.8299x over previous
//
#include <hip/hip_runtime.h>
#include <hip/hip_bf16.h>

typedef unsigned int uint;
typedef unsigned short ushort;
typedef __attribute__((ext_vector_type(8))) short bf16x8;
typedef __attribute__((ext_vector_type(4))) float f32x4;

#define Tn 128
#define Bn 16
#define HH 128
#define G3 384
#define DIN 1024
#define SG 524   // GH row stride in floats (mult of 4; 524%32=12 spreads banks)

__device__ __forceinline__ ushort f2bf(float f){
    union{float f; uint u;} c; c.f = f;
    uint u = c.u + 0x7fffu + ((c.u >> 16) & 1u);   // RNE to bf16
    return (ushort)(u >> 16);
}
__device__ __forceinline__ uint pack2(float a, float b){
    return ((uint)f2bf(b) << 16) | (uint)f2bf(a);
}
__device__ __forceinline__ float sigm(float x){ return 1.f/(1.f + __expf(-x)); }
__device__ __forceinline__ float tanhx(float x){
    float t = __expf(-2.f*fabsf(x));
    float r = (1.f - t)/(1.f + t);
    return x >= 0.f ? r : -r;
}
__device__ __forceinline__ float lo16u(uint u){ union{uint i; float f;} c; c.i = u << 16; return c.f; }
__device__ __forceinline__ float hi16u(uint u){ union{uint i; float f;} c; c.i = u & 0xffff0000u; return c.f; }

// dot of 128: packed-bf16 weight row (64 uints in regs) with fp32 vector in LDS
__device__ __forceinline__ float dot128(const uint* wr, const float* hL){
    float acc = 0.f;
    const float4* h4p = (const float4*)hL;
#pragma unroll
    for (int c = 0; c < 32; ++c){
        float4 h4 = h4p[c];
        uint w0 = wr[2*c], w1 = wr[2*c+1];
        acc = fmaf(lo16u(w0), h4.x, acc);
        acc = fmaf(hi16u(w0), h4.y, acc);
        acc = fmaf(lo16u(w1), h4.z, acc);
        acc = fmaf(hi16u(w1), h4.w, acc);
    }
    return acc;
}
__device__ __forceinline__ void load_row_bf(const float* wrow, uint* wr){
    const float4* wp = (const float4*)wrow;
#pragma unroll
    for (int c = 0; c < 32; ++c){
        float4 q = wp[c];
        wr[2*c]   = pack2(q.x, q.y);
        wr[2*c+1] = pack2(q.z, q.w);
    }
}

// ---------------- emb = x @ W_emb^T : (2048,1024)@(1024,128) -> (2048,128) fp32
__global__ __launch_bounds__(128) void k_emb(const float* __restrict__ x,
                                             const float* __restrict__ Wemb,
                                             float* __restrict__ emb){
    __shared__ __align__(16) float xL[4*DIN];
    int tid = threadIdx.x;
    int row0 = blockIdx.x * 4;
#pragma unroll
    for (int r = 0; r < 4; ++r){
        const float4* src = (const float4*)(x + (size_t)(row0 + r)*DIN);
        float4* dst = (float4*)&xL[r*DIN];
        dst[tid]       = src[tid];
        dst[tid + 128] = src[tid + 128];
    }
    __syncthreads();
    int e = tid;
    float acc0=0.f, acc1=0.f, acc2=0.f, acc3=0.f;
    const float4* wp = (const float4*)(Wemb + (size_t)e*DIN);
#pragma unroll 4
    for (int c = 0; c < 128; ++c){
        float4 qa = wp[2*c], qb = wp[2*c+1];
        int d0 = c*8;
        {
            float4 a = *(const float4*)&xL[0*DIN + d0];
            float4 b = *(const float4*)&xL[0*DIN + d0 + 4];
            acc0 = fmaf(qa.x,a.x,fmaf(qa.y,a.y,fmaf(qa.z,a.z,fmaf(qa.w,a.w,acc0))));
            acc0 = fmaf(qb.x,b.x,fmaf(qb.y,b.y,fmaf(qb.z,b.z,fmaf(qb.w,b.w,acc0))));
        }
        {
            float4 a = *(const float4*)&xL[1*DIN + d0];
            float4 b = *(const float4*)&xL[1*DIN + d0 + 4];
            acc1 = fmaf(qa.x,a.x,fmaf(qa.y,a.y,fmaf(qa.z,a.z,fmaf(qa.w,a.w,acc1))));
            acc1 = fmaf(qb.x,b.x,fmaf(qb.y,b.y,fmaf(qb.z,b.z,fmaf(qb.w,b.w,acc1))));
        }
        {
            float4 a = *(const float4*)&xL[2*DIN + d0];
            float4 b = *(const float4*)&xL[2*DIN + d0 + 4];
            acc2 = fmaf(qa.x,a.x,fmaf(qa.y,a.y,fmaf(qa.z,a.z,fmaf(qa.w,a.w,acc2))));
            acc2 = fmaf(qb.x,b.x,fmaf(qb.y,b.y,fmaf(qb.z,b.z,fmaf(qb.w,b.w,acc2))));
        }
        {
            float4 a = *(const float4*)&xL[3*DIN + d0];
            float4 b = *(const float4*)&xL[3*DIN + d0 + 4];
            acc3 = fmaf(qa.x,a.x,fmaf(qa.y,a.y,fmaf(qa.z,a.z,fmaf(qa.w,a.w,acc3))));
            acc3 = fmaf(qb.x,b.x,fmaf(qb.y,b.y,fmaf(qb.z,b.z,fmaf(qb.w,b.w,acc3))));
        }
    }
    emb[(size_t)(row0+0)*HH + e] = acc0;
    emb[(size_t)(row0+1)*HH + e] = acc1;
    emb[(size_t)(row0+2)*HH + e] = acc2;
    emb[(size_t)(row0+3)*HH + e] = acc3;
}

// ---------------- Gi = emb @ Wih^T + bih, output layout [pos][b][g]; also WoE[pos][b][e]
__global__ __launch_bounds__(768) void k_gi(const float* __restrict__ emb,
                                            const float* __restrict__ Wiha,
                                            const float* __restrict__ biha,
                                            const float* __restrict__ Wihb,
                                            const float* __restrict__ bihb,
                                            const float* __restrict__ Wo,
                                            float* __restrict__ gia,
                                            float* __restrict__ gib,
                                            float* __restrict__ WoE){
    __shared__ __align__(16) float eL[8*HH];
    int tid = threadIdx.x;
    int row0 = blockIdx.x * 8;
    if (tid < 256)
        ((float4*)eL)[tid] = ((const float4*)(emb + (size_t)row0*HH))[tid];
    int g = (tid < G3) ? tid : tid - G3;
    const float* wrow = (tid < G3) ? (Wiha + (size_t)g*HH) : (Wihb + (size_t)g*HH);
    float bias = (tid < G3) ? biha[g] : bihb[g];
    uint wr[64];
    load_row_bf(wrow, wr);
    __syncthreads();
    float* dst = (tid < G3) ? gia : gib;
#pragma unroll
    for (int r = 0; r < 8; ++r){
        int row = row0 + r; int b = row >> 7, pos = row & 127;
        float acc = dot128(wr, &eL[r*HH]) + bias;
        dst[((size_t)(pos*Bn + b))*G3 + g] = acc;
    }
    if (tid < HH){
        float woe = Wo[tid];
#pragma unroll
        for (int r = 0; r < 8; ++r){
            int row = row0 + r; int b = row >> 7, pos = row & 127;
            WoE[((size_t)(pos*Bn + b))*HH + tid] = woe * eL[r*HH + tid];
        }
    }
}

// ---------------- Fused GRU recurrences. grid (128, 2): blockIdx.x -> i (reversed),
// blockIdx.y 0 = GRU-a (emits s), 1 = GRU-b (emits q). 16 chains (all b) per block,
// MFMA 16x16x32 bf16 for the 384(+128)x128 matvec batch.
__global__ __launch_bounds__(512, 2) void k_gru(
    const float* __restrict__ WhhA, const float* __restrict__ bhhA,
    const float* __restrict__ Wa,   const float* __restrict__ ba,
    const float* __restrict__ WhhB, const float* __restrict__ bhhB,
    const float* __restrict__ Wb,   const float* __restrict__ bb,
    const float* __restrict__ GiA,  const float* __restrict__ GiB,
    const float* __restrict__ WoE,
    float* __restrict__ sW, float* __restrict__ qW)
{
    __shared__ __align__(16) ushort HF[256*8];   // H b-frags: row (koct*16+n) = 8 bf16
    __shared__ __align__(16) float  GH[16*SG];   // [n][gate-row 0..511]
    __shared__ float RED[8*16];
    int tid = threadIdx.x;
    int lane = tid & 63, wave = tid >> 6;
    int quad = lane >> 4, mcol = lane & 15;
    int i = Tn - 1 - blockIdx.x;
    int gtype = blockIdx.y;

    const float* Whh = gtype ? WhhB : WhhA;
    const float* bhh = gtype ? bhhB : bhhA;
    const float* Gi  = gtype ? GiB  : GiA;
    int NT = gtype ? 4 : 3;

    // ---- static A-fragments (weights), fp32 -> bf16, once
    bf16x8 afr[4][4];
    for (int u = 0; u < NT; ++u){
        int t = wave + u*8;
        const float* src = (t < 24) ? (Whh + (size_t)(t*16 + mcol)*HH)
                                    : (Wb  + (size_t)((t-24)*16 + mcol)*HH);
#pragma unroll
        for (int kb = 0; kb < 4; ++kb){
            const float* p = src + kb*32 + quad*8;
            float4 a = *(const float4*)p, b2 = *(const float4*)(p+4);
            union { uint4 q; bf16x8 v; } cv;
            cv.q.x = pack2(a.x,a.y);  cv.q.y = pack2(a.z,a.w);
            cv.q.z = pack2(b2.x,b2.y); cv.q.w = pack2(b2.z,b2.w);
            afr[u][kb] = cv.v;
        }
    }

    // ---- updater role: thread = (q4, n); owns h[j] for j = jb..jb+3, chain n
    int q4 = tid >> 4, n = tid & 15, jb = q4*4;
    float bh_r[4], bh_z[4], bh_n[4], wa4[4], bb4[4];
#pragma unroll
    for (int l = 0; l < 4; ++l){
        bh_r[l] = bhh[jb+l]; bh_z[l] = bhh[HH+jb+l]; bh_n[l] = bhh[2*HH+jb+l];
        wa4[l] = gtype ? 0.f : Wa[jb+l];
        bb4[l] = gtype ? bb[jb+l] : 0.f;
    }
    float bav = gtype ? 0.f : ba[0];
    float h4[4] = {0.f,0.f,0.f,0.f};
    if (tid < 256){ uint4 z = {0,0,0,0}; ((uint4*)HF)[tid] = z; }

    // ---- prefetch Gi (pos=i) and WoE (pos=i, consumed at k=1)
    const float* gb = Gi + ((size_t)(i*Bn + n)*G3 + jb);
    float4 pg0 = *(const float4*)(gb);
    float4 pg1 = *(const float4*)(gb + HH);
    float4 pg2 = *(const float4*)(gb + 2*HH);
    float4 pwo = {0.f,0.f,0.f,0.f};
    if (gtype) pwo = *(const float4*)(WoE + ((size_t)(i*Bn + n)*HH + jb));

    __syncthreads();

    for (int k = 0; k <= i; ++k){
        int pos = i - k;
        float4 g0 = pg0, g1 = pg1, g2 = pg2, wo = pwo;
        int pnext = (pos > 0) ? pos - 1 : 0;
        const float* gb2 = Gi + ((size_t)(pnext*Bn + n)*G3 + jb);
        pg0 = *(const float4*)(gb2);
        pg1 = *(const float4*)(gb2 + HH);
        pg2 = *(const float4*)(gb2 + 2*HH);
        if (gtype) pwo = *(const float4*)(WoE + ((size_t)(pos*Bn + n)*HH + jb));

        // ---- MFMA phase: Gh (+Pb) = W @ H
        bf16x8 bfr[4];
#pragma unroll
        for (int f = 0; f < 4; ++f)
            bfr[f] = *(const bf16x8*)&HF[(64*f + lane)*8];
        for (int u = 0; u < NT; ++u){
            f32x4 acc = {0.f,0.f,0.f,0.f};
#pragma unroll
            for (int kb = 0; kb < 4; ++kb)
                acc = __builtin_amdgcn_mfma_f32_16x16x32_bf16(afr[u][kb], bfr[kb], acc, 0,0,0);
            int t = wave + u*8;
            *(f32x4*)&GH[(size_t)mcol*SG + t*16 + quad*4] = acc;
        }
        __syncthreads();   // barrier 1: GH ready

        // ---- gate update (all 512 threads; 4 h-dims each)
        float4 ghr = *(const float4*)&GH[(size_t)n*SG + jb];
        float4 ghz = *(const float4*)&GH[(size_t)n*SG + HH + jb];
        float4 ghn = *(const float4*)&GH[(size_t)n*SG + 2*HH + jb];
        float gr[4] = {ghr.x,ghr.y,ghr.z,ghr.w};
        float gz[4] = {ghz.x,ghz.y,ghz.z,ghz.w};
        float gn[4] = {ghn.x,ghn.y,ghn.z,ghn.w};
        float gi0[4] = {g0.x,g0.y,g0.z,g0.w};
        float gi1[4] = {g1.x,g1.y,g1.z,g1.w};
        float gi2[4] = {g2.x,g2.y,g2.z,g2.w};
#pragma unroll
        for (int l = 0; l < 4; ++l){
            float r = sigm(gi0[l] + gr[l] + bh_r[l]);
            float z = sigm(gi1[l] + gz[l] + bh_z[l]);
            float nn = tanhx(gi2[l] + r*(gn[l] + bh_n[l]));
            h4[l] = (1.f - z)*nn + z*h4[l];
        }
        {   // write new h to B-fragment layout (bf16)
            uint p0 = pack2(h4[0], h4[1]), p1 = pack2(h4[2], h4[3]);
            uint2 hw = {p0, p1};
            *(uint2*)&HF[((jb >> 3)*16 + n)*8 + (jb & 4)] = hw;
        }
        // ---- per-chain scalar: s (gru-a, uses new h) or q for step k-1 (gru-b)
        float part = 0.f;
        if (gtype == 0){
            part = wa4[0]*h4[0] + wa4[1]*h4[1] + wa4[2]*h4[2] + wa4[3]*h4[3];
        } else if (k > 0){
            float4 pb4 = *(const float4*)&GH[(size_t)n*SG + 3*HH + jb];
            float pb[4] = {pb4.x,pb4.y,pb4.z,pb4.w};
            float wof[4] = {wo.x,wo.y,wo.z,wo.w};
#pragma unroll
            for (int l = 0; l < 4; ++l){
                float beta = tanhx(0.5f*pb[l] + bb4[l]);
                part = fmaf(wof[l], beta, part);
            }
        }
        part += __shfl_xor(part, 16);
        part += __shfl_xor(part, 32);
        if (lane < 16) RED[wave*16 + lane] = part;
        __syncthreads();   // barrier 2: HF + RED ready
        if (tid < 16){
            float sum = RED[tid] + RED[16+tid] + RED[32+tid] + RED[48+tid]
                      + RED[64+tid] + RED[80+tid] + RED[96+tid] + RED[112+tid];
            if (gtype == 0)
                sW[((size_t)(tid*Tn + i))*Tn + k] = 0.5f*sum + bav;
            else if (k > 0)
                qW[((size_t)(tid*Tn + i))*Tn + (k-1)] = sum;
        }
    }

    if (gtype){   // tail: Pb for h_i -> q[i]  (WoE[pos=0] was prefetched at k=i)
        bf16x8 bfr[4];
#pragma unroll
        for (int f = 0; f < 4; ++f)
            bfr[f] = *(const bf16x8*)&HF[(64*f + lane)*8];
        f32x4 acc = {0.f,0.f,0.f,0.f};
#pragma unroll
        for (int kb = 0; kb < 4; ++kb)
            acc = __builtin_amdgcn_mfma_f32_16x16x32_bf16(afr[3][kb], bfr[kb], acc, 0,0,0);
        *(f32x4*)&GH[(size_t)mcol*SG + (wave+24)*16 + quad*4] = acc;
        __syncthreads();
        float4 pb4 = *(const float4*)&GH[(size_t)n*SG + 3*HH + jb];
        float pb[4] = {pb4.x,pb4.y,pb4.z,pb4.w};
        float wof[4] = {pwo.x,pwo.y,pwo.z,pwo.w};
        float part = 0.f;
#pragma unroll
        for (int l = 0; l < 4; ++l){
            float beta = tanhx(0.5f*pb[l] + bb4[l]);
            part = fmaf(wof[l], beta, part);
        }
        part += __shfl_xor(part, 16);
        part += __shfl_xor(part, 32);
        if (lane < 16) RED[wave*16 + lane] = part;
        __syncthreads();
        if (tid < 16){
            float sum = RED[tid] + RED[16+tid] + RED[32+tid] + RED[48+tid]
                      + RED[64+tid] + RED[80+tid] + RED[96+tid] + RED[112+tid];
            qW[((size_t)(tid*Tn + i))*Tn + i] = sum;
        }
    }
}

// ---------------- softmax(s) . q per row; one wave per (b,i)
__global__ __launch_bounds__(256) void k_out(const float* __restrict__ sW,
                                             const float* __restrict__ qW,
                                             const float* __restrict__ bo,
                                             float* __restrict__ out){
    int tid = threadIdx.x, lane = tid & 63, w = tid >> 6;
    int r = blockIdx.x*4 + w;
    int i = r & (Tn-1);
    const float* s = sW + (size_t)r*Tn;
    const float* q = qW + (size_t)r*Tn;
    float s0 = (lane     <= i) ? s[lane]      : -1e30f;
    float s1 = (64+lane  <= i) ? s[64+lane]   : -1e30f;
    float m = fmaxf(s0, s1);
#pragma unroll
    for (int off = 32; off; off >>= 1) m = fmaxf(m, __shfl_xor(m, off));
    float e0 = __expf(s0 - m), e1 = __expf(s1 - m);
    float q0 = (lane    <= i) ? q[lane]    : 0.f;
    float q1 = (64+lane <= i) ? q[64+lane] : 0.f;
    float num = e0*q0 + e1*q1, den = e0 + e1;
#pragma unroll
    for (int off = 32; off; off >>= 1){
        num += __shfl_xor(num, off);
        den += __shfl_xor(den, off);
    }
    if (lane == 0) out[r] = num/den + bo[0];
}

extern "C" void kernel_launch(void* const* d_in, const int* in_sizes, int n_in,
                              void* d_out, int out_size, void* d_ws, size_t ws_size,
                              hipStream_t stream) {
    const float* x     = (const float*)d_in[0];
    const float* Wemb  = (const float*)d_in[1];
    const float* Wih_a = (const float*)d_in[2];
    const float* Whh_a = (const float*)d_in[3];
    const float* bih_a = (const float*)d_in[4];
    const float* bhh_a = (const float*)d_in[5];
    const float* Wa    = (const float*)d_in[6];
    const float* ba    = (const float*)d_in[7];
    const float* Wih_b = (const float*)d_in[8];
    const float* Whh_b = (const float*)d_in[9];
    const float* bih_b = (const float*)d_in[10];
    const float* bhh_b = (const float*)d_in[11];
    const float* Wb    = (const float*)d_in[12];
    const float* bb    = (const float*)d_in[13];
    const float* Wo    = (const float*)d_in[14];
    const float* bo    = (const float*)d_in[15];

    const int NR = Bn*Tn;                          // 2048 rows
    float* embW = (float*)d_ws;                    // 2048*128      = 1 MB
    float* giA  = embW + (size_t)NR*HH;            // [pos][b][384] = 3 MB
    float* giB  = giA  + (size_t)NR*G3;            // [pos][b][384] = 3 MB
    float* woE  = giB  + (size_t)NR*G3;            // [pos][b][128] = 1 MB
    float* sW   = woE  + (size_t)NR*HH;            // [b][i][k]     = 1 MB
    float* qW   = sW   + (size_t)NR*Tn;            // [b][i][k]     = 1 MB

    k_emb<<<dim3(NR/4), 128, 0, stream>>>(x, Wemb, embW);
    k_gi <<<dim3(NR/8), 768, 0, stream>>>(embW, Wih_a, bih_a, Wih_b, bih_b, Wo,
                                          giA, giB, woE);
    k_gru<<<dim3(Tn, 2), 512, 0, stream>>>(Whh_a, bhh_a, Wa, ba,
                                           Whh_b, bhh_b, Wb, bb,
                                           giA, giB, woE, sW, qW);
    k_out<<<dim3(NR/4), 256, 0, stream>>>(sW, qW, bo, (float*)d_out);
}

// Round 4
// 356.515 us; speedup vs baseline: 4.7311x; 2.5855x over previous
//
#include <hip/hip_runtime.h>
#include <hip/hip_bf16.h>

typedef unsigned int uint;
typedef unsigned short ushort;
typedef __attribute__((ext_vector_type(8))) short bf16x8;
typedef __attribute__((ext_vector_type(4))) float f32x4;

#define Tn 128
#define Bn 16
#define HH 128
#define G3 384
#define DIN 1024

__device__ __forceinline__ ushort f2bf(float f){
    union{float f; uint u;} c; c.f = f;
    uint u = c.u + 0x7fffu + ((c.u >> 16) & 1u);   // RNE to bf16
    return (ushort)(u >> 16);
}
__device__ __forceinline__ uint pack2(float a, float b){
    return ((uint)f2bf(b) << 16) | (uint)f2bf(a);
}
__device__ __forceinline__ float sigm(float x){ return 1.f/(1.f + __expf(-x)); }
__device__ __forceinline__ float tanhx(float x){
    float t = __expf(-2.f*fabsf(x));
    float r = (1.f - t)/(1.f + t);
    return x >= 0.f ? r : -r;
}
__device__ __forceinline__ float lo16u(uint u){ union{uint i; float f;} c; c.i = u << 16; return c.f; }
__device__ __forceinline__ float hi16u(uint u){ union{uint i; float f;} c; c.i = u & 0xffff0000u; return c.f; }

__device__ __forceinline__ float dot128(const uint* wr, const float* hL){
    float acc = 0.f;
    const float4* h4p = (const float4*)hL;
#pragma unroll
    for (int c = 0; c < 32; ++c){
        float4 h4 = h4p[c];
        uint w0 = wr[2*c], w1 = wr[2*c+1];
        acc = fmaf(lo16u(w0), h4.x, acc);
        acc = fmaf(hi16u(w0), h4.y, acc);
        acc = fmaf(lo16u(w1), h4.z, acc);
        acc = fmaf(hi16u(w1), h4.w, acc);
    }
    return acc;
}
__device__ __forceinline__ void load_row_bf(const float* wrow, uint* wr){
    const float4* wp = (const float4*)wrow;
#pragma unroll
    for (int c = 0; c < 32; ++c){
        float4 q = wp[c];
        wr[2*c]   = pack2(q.x, q.y);
        wr[2*c+1] = pack2(q.z, q.w);
    }
}

// ---------------- emb = x @ W_emb^T : (2048,1024)@(1024,128) -> (2048,128) fp32
__global__ __launch_bounds__(128) void k_emb(const float* __restrict__ x,
                                             const float* __restrict__ Wemb,
                                             float* __restrict__ emb){
    __shared__ __align__(16) float xL[4*DIN];
    int tid = threadIdx.x;
    int row0 = blockIdx.x * 4;
#pragma unroll
    for (int r = 0; r < 4; ++r){
        const float4* src = (const float4*)(x + (size_t)(row0 + r)*DIN);
        float4* dst = (float4*)&xL[r*DIN];
        dst[tid]       = src[tid];
        dst[tid + 128] = src[tid + 128];
    }
    __syncthreads();
    int e = tid;
    float acc0=0.f, acc1=0.f, acc2=0.f, acc3=0.f;
    const float4* wp = (const float4*)(Wemb + (size_t)e*DIN);
#pragma unroll 4
    for (int c = 0; c < 128; ++c){
        float4 qa = wp[2*c], qb = wp[2*c+1];
        int d0 = c*8;
        {
            float4 a = *(const float4*)&xL[0*DIN + d0];
            float4 b = *(const float4*)&xL[0*DIN + d0 + 4];
            acc0 = fmaf(qa.x,a.x,fmaf(qa.y,a.y,fmaf(qa.z,a.z,fmaf(qa.w,a.w,acc0))));
            acc0 = fmaf(qb.x,b.x,fmaf(qb.y,b.y,fmaf(qb.z,b.z,fmaf(qb.w,b.w,acc0))));
        }
        {
            float4 a = *(const float4*)&xL[1*DIN + d0];
            float4 b = *(const float4*)&xL[1*DIN + d0 + 4];
            acc1 = fmaf(qa.x,a.x,fmaf(qa.y,a.y,fmaf(qa.z,a.z,fmaf(qa.w,a.w,acc1))));
            acc1 = fmaf(qb.x,b.x,fmaf(qb.y,b.y,fmaf(qb.z,b.z,fmaf(qb.w,b.w,acc1))));
        }
        {
            float4 a = *(const float4*)&xL[2*DIN + d0];
            float4 b = *(const float4*)&xL[2*DIN + d0 + 4];
            acc2 = fmaf(qa.x,a.x,fmaf(qa.y,a.y,fmaf(qa.z,a.z,fmaf(qa.w,a.w,acc2))));
            acc2 = fmaf(qb.x,b.x,fmaf(qb.y,b.y,fmaf(qb.z,b.z,fmaf(qb.w,b.w,acc2))));
        }
        {
            float4 a = *(const float4*)&xL[3*DIN + d0];
            float4 b = *(const float4*)&xL[3*DIN + d0 + 4];
            acc3 = fmaf(qa.x,a.x,fmaf(qa.y,a.y,fmaf(qa.z,a.z,fmaf(qa.w,a.w,acc3))));
            acc3 = fmaf(qb.x,b.x,fmaf(qb.y,b.y,fmaf(qb.z,b.z,fmaf(qb.w,b.w,acc3))));
        }
    }
    emb[(size_t)(row0+0)*HH + e] = acc0;
    emb[(size_t)(row0+1)*HH + e] = acc1;
    emb[(size_t)(row0+2)*HH + e] = acc2;
    emb[(size_t)(row0+3)*HH + e] = acc3;
}

// ---------------- Gi = emb @ Wih^T + bih, PERMUTED layout [pos][b][P(g)]; WoE[pos][b][e]
// P maps gate-row g=(gamma*128+j) -> tile (3*(j/16)+gamma), row-in-tile (j&15),
// so k_gru's MFMA C-fragments are wave-local to the gate update.
__global__ __launch_bounds__(768) void k_gi(const float* __restrict__ emb,
                                            const float* __restrict__ Wiha,
                                            const float* __restrict__ biha,
                                            const float* __restrict__ Wihb,
                                            const float* __restrict__ bihb,
                                            const float* __restrict__ Wo,
                                            float* __restrict__ gia,
                                            float* __restrict__ gib,
                                            float* __restrict__ WoE){
    __shared__ __align__(16) float eL[8*HH];
    int tid = threadIdx.x;
    int row0 = blockIdx.x * 8;
    if (tid < 256)
        ((float4*)eL)[tid] = ((const float4*)(emb + (size_t)row0*HH))[tid];
    int g = (tid < G3) ? tid : tid - G3;
    const float* wrow = (tid < G3) ? (Wiha + (size_t)g*HH) : (Wihb + (size_t)g*HH);
    float bias = (tid < G3) ? biha[g] : bihb[g];
    uint wr[64];
    load_row_bf(wrow, wr);
    __syncthreads();
    float* dst = (tid < G3) ? gia : gib;
    int gamma = g >> 7, j = g & 127;
    int P = ((3*(j >> 4) + gamma) << 4) + (j & 15);
#pragma unroll
    for (int r = 0; r < 8; ++r){
        int row = row0 + r; int b = row >> 7, pos = row & 127;
        float acc = dot128(wr, &eL[r*HH]) + bias;
        dst[((size_t)(pos*Bn + b))*G3 + P] = acc;
    }
    if (tid < HH){
        float woe = Wo[tid];
#pragma unroll
        for (int r = 0; r < 8; ++r){
            int row = row0 + r; int b = row >> 7, pos = row & 127;
            WoE[((size_t)(pos*Bn + b))*HH + tid] = woe * eL[r*HH + tid];
        }
    }
}

// ---------------- Fused GRU recurrence body, compile-time GT (0=a, 1=b).
// 8 waves, 16 chains (all b); one barrier per step; wave-local gate update.
template<int GT>
__device__ __forceinline__ void gru_body(
    const float* __restrict__ Whh, const float* __restrict__ bhh,
    const float* __restrict__ Wsc, const float* __restrict__ bsc,
    const float* __restrict__ Gi,  const float* __restrict__ WoE,
    float* __restrict__ outW)
{
    constexpr int NT = GT ? 4 : 3;
    __shared__ __align__(16) ushort HF[2][2048];   // h in B-frag order, dbuf
    __shared__ float RED[2][128];                  // per-(wave,chain) partials, dbuf
    int tid = threadIdx.x;
    int lane = tid & 63, u = tid >> 6;
    int quad = lane >> 4, n = lane & 15;
    int i = Tn - 1 - blockIdx.x;
    int jb = u*16 + quad*4;     // 4 h-dims this thread owns (chain n)

    // ---- static A-fragments (row-permuted weights), fully unrolled -> registers
    bf16x8 afr[NT][4];
#pragma unroll
    for (int g = 0; g < NT; ++g){
        const float* src = (g < 3) ? (Whh + (size_t)(g*HH + u*16 + n)*HH)
                                   : (Wsc + (size_t)(u*16 + n)*HH);
#pragma unroll
        for (int kb = 0; kb < 4; ++kb){
            const float* p = src + kb*32 + quad*8;
            float4 a = *(const float4*)p, b2 = *(const float4*)(p+4);
            union { uint4 q; bf16x8 v; } cv;
            cv.q.x = pack2(a.x,a.y);  cv.q.y = pack2(a.z,a.w);
            cv.q.z = pack2(b2.x,b2.y); cv.q.w = pack2(b2.z,b2.w);
            afr[g][kb] = cv.v;
        }
    }
    float bh0[4], bh1[4], bh2[4], wsc4[4];
#pragma unroll
    for (int l = 0; l < 4; ++l){
        bh0[l] = bhh[jb+l]; bh1[l] = bhh[HH+jb+l]; bh2[l] = bhh[2*HH+jb+l];
        wsc4[l] = GT ? bsc[jb+l] : Wsc[jb+l];   // GT1: bb[e]; GT0: Wa[j]
    }
    float bav = GT ? 0.f : bsc[0];
    float h4[4] = {0.f,0.f,0.f,0.f};
    if (tid < 256){ uint4 z = {0,0,0,0}; ((uint4*)HF[1])[tid] = z; }

    const float* gbase = Gi + (size_t)(i*Bn + n)*G3 + u*48 + quad*4;
    float4 pg0 = *(const float4*)(gbase);
    float4 pg1 = *(const float4*)(gbase + 16);
    float4 pg2 = *(const float4*)(gbase + 32);
    float4 pwo = {0.f,0.f,0.f,0.f};
    __syncthreads();

    for (int k = 0; k <= i; ++k){
        int pos = i - k;
        // finish previous step's scalar (pipelined by one step)
        if (tid < 16 && ((GT == 0 && k > 0) || (GT == 1 && k > 1))){
            const float* R = RED[(k+1)&1];
            float sum = R[tid]+R[16+tid]+R[32+tid]+R[48+tid]
                      + R[64+tid]+R[80+tid]+R[96+tid]+R[112+tid];
            int idx = GT ? (k-2) : (k-1);
            outW[((size_t)tid*Tn + i)*Tn + idx] = GT ? sum : (0.5f*sum + bav);
        }
        float4 g0 = pg0, g1 = pg1, g2 = pg2, wo = pwo;
        int pnext = (pos > 0) ? pos - 1 : 0;
        const float* gb2 = Gi + (size_t)(pnext*Bn + n)*G3 + u*48 + quad*4;
        pg0 = *(const float4*)(gb2);
        pg1 = *(const float4*)(gb2 + 16);
        pg2 = *(const float4*)(gb2 + 32);
        if (GT) pwo = *(const float4*)(WoE + (size_t)(pos*Bn + n)*HH + jb);

        const ushort* HR = HF[(k+1)&1];
        bf16x8 bfr[4];
#pragma unroll
        for (int kb = 0; kb < 4; ++kb)
            bfr[kb] = *(const bf16x8*)&HR[(64*kb + lane)*8];

        f32x4 acc[NT];
#pragma unroll
        for (int g = 0; g < NT; ++g){
            f32x4 a_ = {0.f,0.f,0.f,0.f};
#pragma unroll
            for (int kb = 0; kb < 4; ++kb)
                a_ = __builtin_amdgcn_mfma_f32_16x16x32_bf16(afr[g][kb], bfr[kb], a_, 0,0,0);
            acc[g] = a_;
        }

        float part = 0.f;
        if (GT){   // q_{k-1}: Pb(h_{k-1}) with WoE[pos_{k-1}] (prefetched last step)
            float wof[4] = {wo.x, wo.y, wo.z, wo.w};
#pragma unroll
            for (int l = 0; l < 4; ++l){
                float beta = tanhx(0.5f*acc[NT-1][l] + wsc4[l]);
                part = fmaf(wof[l], beta, part);
            }
        }
        float gi0[4]={g0.x,g0.y,g0.z,g0.w}, gi1[4]={g1.x,g1.y,g1.z,g1.w}, gi2[4]={g2.x,g2.y,g2.z,g2.w};
#pragma unroll
        for (int l = 0; l < 4; ++l){
            float r = sigm(gi0[l] + acc[0][l] + bh0[l]);
            float z = sigm(gi1[l] + acc[1][l] + bh1[l]);
            float nn = tanhx(gi2[l] + r*(acc[2][l] + bh2[l]));
            h4[l] = (1.f - z)*nn + z*h4[l];
        }
        if (!GT) part = wsc4[0]*h4[0] + wsc4[1]*h4[1] + wsc4[2]*h4[2] + wsc4[3]*h4[3];

        {
            ushort* HW = HF[k&1];
            uint2 hw = { pack2(h4[0], h4[1]), pack2(h4[2], h4[3]) };
            *(uint2*)&HW[((jb>>3)*16 + n)*8 + (jb&4)] = hw;
        }
        part += __shfl_xor(part, 16);
        part += __shfl_xor(part, 32);
        if (lane < 16) RED[k&1][u*16 + n] = part;
        __syncthreads();
    }

    // ---- tail
    if (tid < 16){
        const float* R = RED[i&1];
        float sum = R[tid]+R[16+tid]+R[32+tid]+R[48+tid]
                  + R[64+tid]+R[80+tid]+R[96+tid]+R[112+tid];
        if (GT == 0)      outW[((size_t)tid*Tn + i)*Tn + i] = 0.5f*sum + bav;
        else if (i > 0)   outW[((size_t)tid*Tn + i)*Tn + (i-1)] = sum;
    }
    if (GT){   // q_i: Pb(h_i) with WoE[0] (in pwo)
        const ushort* HR = HF[i&1];
        bf16x8 bfr[4];
#pragma unroll
        for (int kb = 0; kb < 4; ++kb)
            bfr[kb] = *(const bf16x8*)&HR[(64*kb + lane)*8];
        f32x4 a_ = {0.f,0.f,0.f,0.f};
#pragma unroll
        for (int kb = 0; kb < 4; ++kb)
            a_ = __builtin_amdgcn_mfma_f32_16x16x32_bf16(afr[NT-1][kb], bfr[kb], a_, 0,0,0);
        float wof[4] = {pwo.x, pwo.y, pwo.z, pwo.w};
        float part = 0.f;
#pragma unroll
        for (int l = 0; l < 4; ++l){
            float beta = tanhx(0.5f*a_[l] + wsc4[l]);
            part = fmaf(wof[l], beta, part);
        }
        part += __shfl_xor(part, 16);
        part += __shfl_xor(part, 32);
        if (lane < 16) RED[(i+1)&1][u*16 + n] = part;
        __syncthreads();
        if (tid < 16){
            const float* R = RED[(i+1)&1];
            float sum = R[tid]+R[16+tid]+R[32+tid]+R[48+tid]
                      + R[64+tid]+R[80+tid]+R[96+tid]+R[112+tid];
            outW[((size_t)tid*Tn + i)*Tn + i] = sum;
        }
    }
}

__global__ __launch_bounds__(512, 2) void k_gru(
    const float* __restrict__ WhhA, const float* __restrict__ bhhA,
    const float* __restrict__ Wa,   const float* __restrict__ ba,
    const float* __restrict__ WhhB, const float* __restrict__ bhhB,
    const float* __restrict__ Wb,   const float* __restrict__ bb,
    const float* __restrict__ GiA,  const float* __restrict__ GiB,
    const float* __restrict__ WoE,
    float* __restrict__ sW, float* __restrict__ qW)
{
    if (blockIdx.y == 0) gru_body<0>(WhhA, bhhA, Wa, ba, GiA, nullptr, sW);
    else                 gru_body<1>(WhhB, bhhB, Wb, bb, GiB, WoE,    qW);
}

// ---------------- softmax(s) . q per row; one wave per (b,i)
__global__ __launch_bounds__(256) void k_out(const float* __restrict__ sW,
                                             const float* __restrict__ qW,
                                             const float* __restrict__ bo,
                                             float* __restrict__ out){
    int tid = threadIdx.x, lane = tid & 63, w = tid >> 6;
    int r = blockIdx.x*4 + w;
    int i = r & (Tn-1);
    const float* s = sW + (size_t)r*Tn;
    const float* q = qW + (size_t)r*Tn;
    float s0 = (lane     <= i) ? s[lane]      : -1e30f;
    float s1 = (64+lane  <= i) ? s[64+lane]   : -1e30f;
    float m = fmaxf(s0, s1);
#pragma unroll
    for (int off = 32; off; off >>= 1) m = fmaxf(m, __shfl_xor(m, off));
    float e0 = __expf(s0 - m), e1 = __expf(s1 - m);
    float q0 = (lane    <= i) ? q[lane]    : 0.f;
    float q1 = (64+lane <= i) ? q[64+lane] : 0.f;
    float num = e0*q0 + e1*q1, den = e0 + e1;
#pragma unroll
    for (int off = 32; off; off >>= 1){
        num += __shfl_xor(num, off);
        den += __shfl_xor(den, off);
    }
    if (lane == 0) out[r] = num/den + bo[0];
}

extern "C" void kernel_launch(void* const* d_in, const int* in_sizes, int n_in,
                              void* d_out, int out_size, void* d_ws, size_t ws_size,
                              hipStream_t stream) {
    const float* x     = (const float*)d_in[0];
    const float* Wemb  = (const float*)d_in[1];
    const float* Wih_a = (const float*)d_in[2];
    const float* Whh_a = (const float*)d_in[3];
    const float* bih_a = (const float*)d_in[4];
    const float* bhh_a = (const float*)d_in[5];
    const float* Wa    = (const float*)d_in[6];
    const float* ba    = (const float*)d_in[7];
    const float* Wih_b = (const float*)d_in[8];
    const float* Whh_b = (const float*)d_in[9];
    const float* bih_b = (const float*)d_in[10];
    const float* bhh_b = (const float*)d_in[11];
    const float* Wb    = (const float*)d_in[12];
    const float* bb    = (const float*)d_in[13];
    const float* Wo    = (const float*)d_in[14];
    const float* bo    = (const float*)d_in[15];

    const int NR = Bn*Tn;                          // 2048 rows
    float* embW = (float*)d_ws;                    // 2048*128
    float* giA  = embW + (size_t)NR*HH;            // [pos][b][384] permuted
    float* giB  = giA  + (size_t)NR*G3;
    float* woE  = giB  + (size_t)NR*G3;            // [pos][b][128]
    float* sW   = woE  + (size_t)NR*HH;            // [b][i][k]
    float* qW   = sW   + (size_t)NR*Tn;            // [b][i][k]

    k_emb<<<dim3(NR/4), 128, 0, stream>>>(x, Wemb, embW);
    k_gi <<<dim3(NR/8), 768, 0, stream>>>(embW, Wih_a, bih_a, Wih_b, bih_b, Wo,
                                          giA, giB, woE);
    k_gru<<<dim3(Tn, 2), 512, 0, stream>>>(Whh_a, bhh_a, Wa, ba,
                                           Whh_b, bhh_b, Wb, bb,
                                           giA, giB, woE, sW, qW);
    k_out<<<dim3(NR/4), 256, 0, stream>>>(sW, qW, bo, (float*)d_out);
}